// Round 1
// baseline (58.634 us; speedup 1.0000x reference)
//
#include <hip/hip_runtime.h>
#include <math.h>

// Problem: AnatomicalConsistencyLoss — fused Sobel-gradient magnitude + cosine loss.
// Shapes: pred/target (2,1,160,160,160) f32; output: scalar f32.

constexpr int Dd = 160, Hh = 160, Ww = 160;
constexpr int TW = 32, TH = 8, DC = 20;     // tile: 32(W) x 8(H), 20 planes per block
constexpr int PW = TW + 2;                  // 34
constexpr int PH = TH + 2;                  // 10
constexpr int PLANE = PH * PW;              // 340
constexpr int NB_X = (Ww / TW) * (Hh / TH); // 5*20 = 100
constexpr int NB_Y = Dd / DC;               // 8
constexpr int NB_Z = 2;                     // batch
constexpr int NBLOCKS = NB_X * NB_Y * NB_Z; // 1600
constexpr double NVOX = 2.0 * Dd * Hh * Ww; // 8,192,000

__global__ __launch_bounds__(256)
void acl_partial(const float* __restrict__ pred, const float* __restrict__ targ,
                 float2* __restrict__ partial)
{
    __shared__ float sp[2][PLANE];
    __shared__ float st[2][PLANE];
    __shared__ float rmag[4], rcos[4];

    const int tid = threadIdx.x;
    const int tw = tid & 31;
    const int th = tid >> 5;

    const int wt = blockIdx.x % 5;
    const int ht = blockIdx.x / 5;
    const int z0 = blockIdx.y * DC;
    const int b  = blockIdx.z;

    const int x0 = wt * TW;
    const int y0 = ht * TH;
    const size_t base = (size_t)b * ((size_t)Dd * Hh * Ww);

    // 3-plane register rings (shift-based: all indices static)
    float Ap0=0.f,Ap1=0.f,Ap2=0.f, Bp0=0.f,Bp1=0.f,Bp2=0.f, Cp0=0.f,Cp1=0.f,Cp2=0.f;
    float At0=0.f,At1=0.f,At2=0.f, Bt0=0.f,Bt1=0.f,Bt2=0.f, Ct0=0.f,Ct1=0.f,Ct2=0.f;
    float acc_mag = 0.f, acc_cos = 0.f;

    auto loadPlane = [&](int p, int buf) {
        const int gz = z0 - 1 + p;
        const bool zok = ((unsigned)gz < (unsigned)Dd);
        const size_t zoff = base + (size_t)gz * (Hh * Ww);
        #pragma unroll
        for (int i0 = 0; i0 < 2; ++i0) {
            const int i = tid + i0 * 256;
            if (i < PLANE) {
                const int ph = i / PW;
                const int pw = i - ph * PW;
                const int gy = y0 - 1 + ph;
                const int gx = x0 - 1 + pw;
                float vp = 0.f, vt = 0.f;
                if (zok && (unsigned)gy < (unsigned)Hh && (unsigned)gx < (unsigned)Ww) {
                    const size_t idx = zoff + (size_t)gy * Ww + gx;
                    vp = pred[idx];
                    vt = targ[idx];
                }
                sp[buf][i] = vp;
                st[buf][i] = vt;
            }
        }
    };

    loadPlane(0, 0);
    __syncthreads();

    for (int p = 0; p <= DC + 1; ++p) {
        const int buf = p & 1;
        if (p < DC + 1) loadPlane(p + 1, buf ^ 1);

        const int r0 = th * PW + tw;  // top-left of this thread's 3x3 in-plane window

        // pred in-plane combos
        {
            const float* s = sp[buf];
            const float a0 = s[r0],        b0 = s[r0+1],        c0 = s[r0+2];
            const float a1 = s[r0+PW],     b1 = s[r0+PW+1],     c1 = s[r0+PW+2];
            const float a2 = s[r0+2*PW],   b2 = s[r0+2*PW+1],   c2 = s[r0+2*PW+2];
            const float rs0 = a0 + 2.f*b0 + c0, rd0 = c0 - a0;
            const float rs1 = a1 + 2.f*b1 + c1, rd1 = c1 - a1;
            const float rs2 = a2 + 2.f*b2 + c2, rd2 = c2 - a2;
            Ap0 = Ap1; Ap1 = Ap2; Ap2 = rs0 + 2.f*rs1 + rs2;  // smooth_h(smooth_w)
            Bp0 = Bp1; Bp1 = Bp2; Bp2 = rd0 + 2.f*rd1 + rd2;  // smooth_h(deriv_w)
            Cp0 = Cp1; Cp1 = Cp2; Cp2 = rs2 - rs0;            // deriv_h(smooth_w)
        }
        // target in-plane combos
        {
            const float* s = st[buf];
            const float a0 = s[r0],        b0 = s[r0+1],        c0 = s[r0+2];
            const float a1 = s[r0+PW],     b1 = s[r0+PW+1],     c1 = s[r0+PW+2];
            const float a2 = s[r0+2*PW],   b2 = s[r0+2*PW+1],   c2 = s[r0+2*PW+2];
            const float rs0 = a0 + 2.f*b0 + c0, rd0 = c0 - a0;
            const float rs1 = a1 + 2.f*b1 + c1, rd1 = c1 - a1;
            const float rs2 = a2 + 2.f*b2 + c2, rd2 = c2 - a2;
            At0 = At1; At1 = At2; At2 = rs0 + 2.f*rs1 + rs2;
            Bt0 = Bt1; Bt1 = Bt2; Bt2 = rd0 + 2.f*rd1 + rd2;
            Ct0 = Ct1; Ct1 = Ct2; Ct2 = rs2 - rs0;
        }

        if (p >= 2) {
            // gradients at output plane z0 + (p-2)
            const float gxp = Bp0 + 2.f*Bp1 + Bp2;
            const float gyp = Cp0 + 2.f*Cp1 + Cp2;
            const float gzp = Ap2 - Ap0;
            const float gxt = Bt0 + 2.f*Bt1 + Bt2;
            const float gyt = Ct0 + 2.f*Ct1 + Ct2;
            const float gzt = At2 - At0;

            const float np2 = gxp*gxp + gyp*gyp + gzp*gzp;
            const float nt2 = gxt*gxt + gyt*gyt + gzt*gzt;

            // magnitude loss term
            const float pm = sqrtf(np2 + 1e-8f);
            const float tm = sqrtf(nt2 + 1e-8f);
            const float dm = pm - tm;
            acc_mag += dm * dm;

            // direction term: F.normalize(eps=1e-12) then cosine_similarity(eps=1e-8)
            const float normp = sqrtf(np2);
            const float normt = sqrtf(nt2);
            const float denp = fmaxf(normp, 1e-12f);
            const float dent = fmaxf(normt, 1e-12f);
            const float na = (normp >= 1e-12f) ? 1.0f : fmaxf(normp * 1e12f, 1e-8f);
            const float nb = (normt >= 1e-12f) ? 1.0f : fmaxf(normt * 1e12f, 1e-8f);
            const float dot = gxp*gxt + gyp*gyt + gzp*gzt;
            acc_cos += dot / (denp * dent * na * nb);
        }
        __syncthreads();
    }

    // block reduction: wave64 shuffle then cross-wave via LDS
    #pragma unroll
    for (int off = 32; off >= 1; off >>= 1) {
        acc_mag += __shfl_down(acc_mag, off);
        acc_cos += __shfl_down(acc_cos, off);
    }
    const int wid = tid >> 6;
    if ((tid & 63) == 0) { rmag[wid] = acc_mag; rcos[wid] = acc_cos; }
    __syncthreads();
    if (tid == 0) {
        const float m = rmag[0] + rmag[1] + rmag[2] + rmag[3];
        const float c = rcos[0] + rcos[1] + rcos[2] + rcos[3];
        const int bid = (blockIdx.z * gridDim.y + blockIdx.y) * gridDim.x + blockIdx.x;
        partial[bid] = make_float2(m, c);
    }
}

__global__ __launch_bounds__(256)
void acl_final(const float2* __restrict__ partial, float* __restrict__ out)
{
    __shared__ double sm[256], sc[256];
    double m = 0.0, c = 0.0;
    for (int i = threadIdx.x; i < NBLOCKS; i += 256) {
        const float2 v = partial[i];
        m += (double)v.x;
        c += (double)v.y;
    }
    sm[threadIdx.x] = m;
    sc[threadIdx.x] = c;
    __syncthreads();
    #pragma unroll
    for (int s = 128; s >= 1; s >>= 1) {
        if (threadIdx.x < (unsigned)s) {
            sm[threadIdx.x] += sm[threadIdx.x + s];
            sc[threadIdx.x] += sc[threadIdx.x + s];
        }
        __syncthreads();
    }
    if (threadIdx.x == 0) {
        const double mag_loss = sm[0] / NVOX;
        const double dir_loss = 1.0 - sc[0] / NVOX;
        out[0] = (float)(0.2 * (mag_loss + dir_loss));
    }
}

extern "C" void kernel_launch(void* const* d_in, const int* in_sizes, int n_in,
                              void* d_out, int out_size, void* d_ws, size_t ws_size,
                              hipStream_t stream) {
    const float* pred = (const float*)d_in[0];
    const float* targ = (const float*)d_in[1];
    float* out = (float*)d_out;
    float2* partial = (float2*)d_ws;  // needs 1600 * 8 B = 12.8 KB

    dim3 grid(NB_X, NB_Y, NB_Z);  // (100, 8, 2)
    acl_partial<<<grid, 256, 0, stream>>>(pred, targ, partial);
    acl_final<<<1, 256, 0, stream>>>(partial, out);
}

// Round 2
// 49.263 us; speedup vs baseline: 1.1902x; 1.1902x over previous
//
#include <hip/hip_runtime.h>

// AnatomicalConsistencyLoss: fused separable-Sobel magnitude + cosine loss.
// pred/target (2,1,160,160,160) f32 -> scalar f32.
// Structure: per block, 32(x)*32(y) tile marching DC planes in z.
// Stage A: global -> horizontal combos (HS=smooth_w, HD=deriv_w) in LDS (once per row).
// Stage B: vertical combine (A=sm_h(HS), B=sm_h(HD), C=d_h(HS)), 3-deep z-ring in regs,
//          depth combine -> gradients -> loss terms, fp32 per-thread accum.

constexpr int Dd = 160, Hh = 160, Ww = 160;
constexpr int TW = 32, TH = 32, DC = 8;
constexpr int NTX = Ww / TW;                 // 5
constexpr int NB_X = NTX * (Hh / TH);        // 25
constexpr int NB_Y = Dd / DC;                // 20
constexpr int NB_Z = 2;
constexpr int NBLOCKS = NB_X * NB_Y * NB_Z;  // 1000
constexpr int PLANES = DC + 2;               // 10
constexpr size_t PLSZ = (size_t)Hh * Ww;     // 25600
constexpr double NVOX = 2.0 * Dd * Hh * Ww;  // 8,192,000

__device__ __forceinline__ float4 sm3(const float4 a, const float4 b, const float4 c) {
    // a + 2b + c
    return make_float4(a.x + 2.f*b.x + c.x, a.y + 2.f*b.y + c.y,
                       a.z + 2.f*b.z + c.z, a.w + 2.f*b.w + c.w);
}
__device__ __forceinline__ float4 df2(const float4 a, const float4 c) {
    // c - a
    return make_float4(c.x - a.x, c.y - a.y, c.z - a.z, c.w - a.w);
}
__device__ __forceinline__ float4 mul4(const float4 a, const float4 b) {
    return make_float4(a.x*b.x, a.y*b.y, a.z*b.z, a.w*b.w);
}
__device__ __forceinline__ float4 fma4(const float4 a, const float4 b, const float4 c) {
    return make_float4(fmaf(a.x,b.x,c.x), fmaf(a.y,b.y,c.y),
                       fmaf(a.z,b.z,c.z), fmaf(a.w,b.w,c.w));
}
__device__ __forceinline__ float4 sub4(const float4 a, const float4 b) {
    return make_float4(a.x-b.x, a.y-b.y, a.z-b.z, a.w-b.w);
}
__device__ __forceinline__ float4 adds4(const float4 a, const float s) {
    return make_float4(a.x+s, a.y+s, a.z+s, a.w+s);
}
__device__ __forceinline__ float4 maxs4(const float4 a, const float s) {
    return make_float4(fmaxf(a.x,s), fmaxf(a.y,s), fmaxf(a.z,s), fmaxf(a.w,s));
}
__device__ __forceinline__ float4 sqrt4(const float4 a) {
    return make_float4(__builtin_amdgcn_sqrtf(a.x), __builtin_amdgcn_sqrtf(a.y),
                       __builtin_amdgcn_sqrtf(a.z), __builtin_amdgcn_sqrtf(a.w));
}
__device__ __forceinline__ float4 rsq4(const float4 a) {
    return make_float4(__builtin_amdgcn_rsqf(a.x), __builtin_amdgcn_rsqf(a.y),
                       __builtin_amdgcn_rsqf(a.z), __builtin_amdgcn_rsqf(a.w));
}

__global__ __launch_bounds__(256, 4)
void acl_partial(const float* __restrict__ pred, const float* __restrict__ targ,
                 float2* __restrict__ partial)
{
    // combos: [34 rows][8 x-groups] float4; row stride 128B -> wave accesses contiguous
    __shared__ float4 sHSp[TH + 2][8], sHDp[TH + 2][8];
    __shared__ float4 sHSt[TH + 2][8], sHDt[TH + 2][8];
    __shared__ float rred[8];

    const int tid = threadIdx.x;
    const int gx  = tid & 7;          // x-group (4 floats each)
    const int r   = tid >> 3;         // row 0..31

    const int wt = blockIdx.x % NTX;
    const int ht = blockIdx.x / NTX;
    const int x0 = wt * TW, y0 = ht * TH;
    const int z0 = blockIdx.y * DC;
    const size_t base = (size_t)blockIdx.z * ((size_t)Dd * PLSZ);

    const float* __restrict__ pv = pred + base;
    const float* __restrict__ tv = targ + base;

    // stage-A group 1: row r (padded rows 0..31), group 2 (tid<16): rows 32,33
    const int xA   = x0 + gx * 4;
    const bool xmok = (xA > 0);
    const bool xpok = (xA + 4 < Ww);

    const int yA1  = y0 - 1 + r;
    const bool yok1 = (unsigned)yA1 < (unsigned)Hh;
    const int ro1  = yA1 * Ww + xA;

    const bool has2 = (tid < 16);
    const int r2   = TH + (tid >> 3);             // 32 or 33
    const int yA2  = y0 - 1 + r2;
    const bool yok2 = has2 && ((unsigned)yA2 < (unsigned)Hh);
    const int ro2  = yA2 * Ww + xA;

    auto loadCombo = [&](const float* __restrict__ plane, int rowoff, bool vok,
                         float4& HS, float4& HD) {
        float e0 = 0.f, e1 = 0.f, e2 = 0.f, e3 = 0.f, e4 = 0.f, e5 = 0.f;
        if (vok) {
            const float* rp = plane + rowoff;
            const float4 v = *(const float4*)rp;
            e1 = v.x; e2 = v.y; e3 = v.z; e4 = v.w;
            if (xmok) e0 = rp[-1];
            if (xpok) e5 = rp[4];
        }
        HS = make_float4(e0 + 2.f*e1 + e2, e1 + 2.f*e2 + e3,
                         e2 + 2.f*e3 + e4, e3 + 2.f*e4 + e5);
        HD = make_float4(e2 - e0, e3 - e1, e4 - e2, e5 - e3);
    };

    float4 Ap[3], Bp[3], Cp[3], At[3], Bt[3], Ct[3];
    float4 accm = make_float4(0.f,0.f,0.f,0.f);
    float4 accc = make_float4(0.f,0.f,0.f,0.f);

    #pragma unroll
    for (int p = 0; p < PLANES; ++p) {
        // ---- stage A: write horizontal combos for plane gz = z0-1+p ----
        {
            const int gz = z0 - 1 + p;
            const bool zok = (unsigned)gz < (unsigned)Dd;  // wave-uniform
            float4 hsp, hdp, hst, hdt;
            if (zok) {
                const float* pz = pv + (size_t)gz * PLSZ;
                const float* tz = tv + (size_t)gz * PLSZ;
                loadCombo(pz, ro1, yok1, hsp, hdp);
                loadCombo(tz, ro1, yok1, hst, hdt);
            } else {
                hsp = hdp = hst = hdt = make_float4(0.f,0.f,0.f,0.f);
            }
            sHSp[r][gx] = hsp; sHDp[r][gx] = hdp;
            sHSt[r][gx] = hst; sHDt[r][gx] = hdt;
            if (has2) {
                float4 hsp2, hdp2, hst2, hdt2;
                if (zok) {
                    const float* pz = pv + (size_t)gz * PLSZ;
                    const float* tz = tv + (size_t)gz * PLSZ;
                    loadCombo(pz, ro2, yok2, hsp2, hdp2);
                    loadCombo(tz, ro2, yok2, hst2, hdt2);
                } else {
                    hsp2 = hdp2 = hst2 = hdt2 = make_float4(0.f,0.f,0.f,0.f);
                }
                sHSp[r2][gx] = hsp2; sHDp[r2][gx] = hdp2;
                sHSt[r2][gx] = hst2; sHDt[r2][gx] = hdt2;
            }
        }
        __syncthreads();

        // ---- stage B: vertical combine into z-ring ----
        {
            const int s2 = p % 3;  // static after unroll
            {
                const float4 hs0 = sHSp[r][gx], hs1 = sHSp[r+1][gx], hs2 = sHSp[r+2][gx];
                const float4 hd0 = sHDp[r][gx], hd1 = sHDp[r+1][gx], hd2 = sHDp[r+2][gx];
                Ap[s2] = sm3(hs0, hs1, hs2);
                Cp[s2] = df2(hs0, hs2);
                Bp[s2] = sm3(hd0, hd1, hd2);
            }
            {
                const float4 hs0 = sHSt[r][gx], hs1 = sHSt[r+1][gx], hs2 = sHSt[r+2][gx];
                const float4 hd0 = sHDt[r][gx], hd1 = sHDt[r+1][gx], hd2 = sHDt[r+2][gx];
                At[s2] = sm3(hs0, hs1, hs2);
                Ct[s2] = df2(hs0, hs2);
                Bt[s2] = sm3(hd0, hd1, hd2);
            }
        }

        if (p >= 2) {
            const int s0 = (p - 2) % 3, s1 = (p - 1) % 3, s2 = p % 3;
            const float4 gxp = sm3(Bp[s0], Bp[s1], Bp[s2]);
            const float4 gyp = sm3(Cp[s0], Cp[s1], Cp[s2]);
            const float4 gzp = df2(Ap[s0], Ap[s2]);
            const float4 gxt = sm3(Bt[s0], Bt[s1], Bt[s2]);
            const float4 gyt = sm3(Ct[s0], Ct[s1], Ct[s2]);
            const float4 gzt = df2(At[s0], At[s2]);

            const float4 np2 = fma4(gxp, gxp, fma4(gyp, gyp, mul4(gzp, gzp)));
            const float4 nt2 = fma4(gxt, gxt, fma4(gyt, gyt, mul4(gzt, gzt)));

            // magnitude term
            const float4 pm = sqrt4(adds4(np2, 1e-8f));
            const float4 tm = sqrt4(adds4(nt2, 1e-8f));
            const float4 dm = sub4(pm, tm);
            accm = fma4(dm, dm, accm);

            // direction term: dot / (||gp|| * ||gt||); eps guards unreachable for
            // nonzero grads (norm >= 1e-12 -> na=nb=1), dot==0 when a grad is 0.
            const float4 dot = fma4(gxp, gxt, fma4(gyp, gyt, mul4(gzp, gzt)));
            const float4 ra = rsq4(maxs4(np2, 1e-30f));
            const float4 rb = rsq4(maxs4(nt2, 1e-30f));
            accc = fma4(mul4(dot, ra), rb, accc);
        }
        __syncthreads();   // protect LDS before next stage-A overwrite
    }

    // block reduction
    float am = accm.x + accm.y + accm.z + accm.w;
    float ac = accc.x + accc.y + accc.z + accc.w;
    #pragma unroll
    for (int off = 32; off >= 1; off >>= 1) {
        am += __shfl_down(am, off);
        ac += __shfl_down(ac, off);
    }
    const int wid = tid >> 6;
    if ((tid & 63) == 0) { rred[wid] = am; rred[4 + wid] = ac; }
    __syncthreads();
    if (tid == 0) {
        const float m = rred[0] + rred[1] + rred[2] + rred[3];
        const float c = rred[4] + rred[5] + rred[6] + rred[7];
        const int bid = (blockIdx.z * gridDim.y + blockIdx.y) * gridDim.x + blockIdx.x;
        partial[bid] = make_float2(m, c);
    }
}

__global__ __launch_bounds__(256)
void acl_final(const float2* __restrict__ partial, float* __restrict__ out)
{
    __shared__ double sm[256], sc[256];
    double m = 0.0, c = 0.0;
    for (int i = threadIdx.x; i < NBLOCKS; i += 256) {
        const float2 v = partial[i];
        m += (double)v.x;
        c += (double)v.y;
    }
    sm[threadIdx.x] = m;
    sc[threadIdx.x] = c;
    __syncthreads();
    #pragma unroll
    for (int s = 128; s >= 1; s >>= 1) {
        if (threadIdx.x < (unsigned)s) {
            sm[threadIdx.x] += sm[threadIdx.x + s];
            sc[threadIdx.x] += sc[threadIdx.x + s];
        }
        __syncthreads();
    }
    if (threadIdx.x == 0) {
        const double mag_loss = sm[0] / NVOX;
        const double dir_loss = 1.0 - sc[0] / NVOX;
        out[0] = (float)(0.2 * (mag_loss + dir_loss));
    }
}

extern "C" void kernel_launch(void* const* d_in, const int* in_sizes, int n_in,
                              void* d_out, int out_size, void* d_ws, size_t ws_size,
                              hipStream_t stream) {
    const float* pred = (const float*)d_in[0];
    const float* targ = (const float*)d_in[1];
    float* out = (float*)d_out;
    float2* partial = (float2*)d_ws;  // 1000 * 8 B = 8 KB

    dim3 grid(NB_X, NB_Y, NB_Z);  // (25, 20, 2)
    acl_partial<<<grid, 256, 0, stream>>>(pred, targ, partial);
    acl_final<<<1, 256, 0, stream>>>(partial, out);
}